// Round 2
// baseline (10085.751 us; speedup 1.0000x reference)
//
#include <hip/hip_runtime.h>
#include <math.h>

#define B_ 1024
#define S_ 50
#define D_ 96
#define H_ 8
#define DH_ 12
#define DF_ 192
#define L_ 3
#define NC_ 3
#define V_ 40000

__device__ __forceinline__ float dot4f(float4 a, float4 b) {
  return a.x*b.x + a.y*b.y + a.z*b.z + a.w*b.w;
}
__device__ __forceinline__ float geluf(float v) {
  return 0.5f*v*(1.0f + erff(v*0.70710678118654752f));
}

// ---------------- embedding ----------------
__global__ void k_embed(const int* __restrict__ loc, const int* __restrict__ users,
                        const int* __restrict__ mins, const int* __restrict__ wd,
                        const float* __restrict__ loc_emb, const float* __restrict__ user_emb,
                        const float* __restrict__ hour_emb, const float* __restrict__ wd_emb,
                        const float* __restrict__ temp_w, const float* __restrict__ temp_b,
                        const float* __restrict__ pos, float* __restrict__ x)
{
  int bs = blockIdx.x; int b = bs / S_; int s = bs % S_;
  __shared__ float tmp[48];
  int t = threadIdx.x;
  if (t < 48) {
    int hr = (mins[bs] / 60) % 24;
    int w  = wd[bs];
    tmp[t] = (t < 24) ? hour_emb[hr*24 + t] : wd_emb[w*24 + (t-24)];
  }
  __syncthreads();
  int lc = loc[bs]; int u = users[b*S_];
  float acc = temp_b[t] + loc_emb[(size_t)lc*D_ + t] + user_emb[(size_t)u*D_ + t] + pos[s*D_ + t];
  const float* twr = temp_w + t*48;
  #pragma unroll
  for (int k = 0; k < 48; k++) acc += tmp[k] * twr[k];
  x[(size_t)bs*D_ + t] = acc;
}

// ---------------- init hidden ----------------
__global__ void k_init(const float* __restrict__ init_hidden, float* __restrict__ hidden) {
  int i = blockIdx.x*256 + threadIdx.x;
  if (i < B_*D_) hidden[i] = init_hidden[i % D_];
}

// ---------------- fused self-attention (QKV proj in-kernel), one block per (b,h) ----------------
__global__ __launch_bounds__(64) void k_attn(const float* __restrict__ x,
                                             const float* __restrict__ wi,
                                             const float* __restrict__ bi,
                                             float* __restrict__ out)
{
  int bh = blockIdx.x; int b = bh >> 3; int h = bh & 7;
  __shared__ __align__(16) float xs[S_*100];
  __shared__ __align__(16) float qs[S_*DH_], ks[S_*DH_], vs[S_*DH_];
  int tid = threadIdx.x;
  const float* xb = x + (size_t)b*S_*D_;
  for (int idx = tid; idx < S_*24; idx += 64) {
    int r = idx/24, q = idx%24;
    *(float4*)&xs[r*100 + q*4] = *(const float4*)&xb[r*D_ + q*4];
  }
  __syncthreads();
  // project q,k,v head-slices: 3 * 50 * 12 outputs
  for (int idx = tid; idx < 3*S_*DH_; idx += 64) {
    int m = idx / (S_*DH_); int rem = idx % (S_*DH_);
    int s = rem / DH_; int dh = rem % DH_;
    int wrow = m*D_ + h*DH_ + dh;
    const float* wr = wi + (size_t)wrow*D_;
    float acc = bi[wrow];
    #pragma unroll
    for (int d = 0; d < D_; d += 4) {
      float4 a = *(float4*)&xs[s*100 + d];
      float4 w = *(const float4*)&wr[d];
      acc += dot4f(a, w);
    }
    float* dst = (m == 0) ? qs : (m == 1) ? ks : vs;
    dst[s*DH_ + dh] = acc;
  }
  __syncthreads();
  int i = tid;
  if (i < S_) {
    float q[DH_];
    #pragma unroll
    for (int d = 0; d < DH_; d++) q[d] = qs[i*DH_ + d];
    float p[S_]; float mx = -1e30f;
    #pragma unroll
    for (int s = 0; s < S_; s++) {
      float4 k0 = *(float4*)&ks[s*DH_ + 0];
      float4 k1 = *(float4*)&ks[s*DH_ + 4];
      float4 k2 = *(float4*)&ks[s*DH_ + 8];
      float acc = q[0]*k0.x + q[1]*k0.y + q[2]*k0.z + q[3]*k0.w
                + q[4]*k1.x + q[5]*k1.y + q[6]*k1.z + q[7]*k1.w
                + q[8]*k2.x + q[9]*k2.y + q[10]*k2.z + q[11]*k2.w;
      acc *= 0.28867513459481287f;
      p[s] = acc; mx = fmaxf(mx, acc);
    }
    float sum = 0.f;
    #pragma unroll
    for (int s = 0; s < S_; s++) { p[s] = expf(p[s] - mx); sum += p[s]; }
    float inv = 1.f / sum;
    float o[DH_];
    #pragma unroll
    for (int d = 0; d < DH_; d++) o[d] = 0.f;
    #pragma unroll
    for (int s = 0; s < S_; s++) {
      float4 v0 = *(float4*)&vs[s*DH_ + 0];
      float4 v1 = *(float4*)&vs[s*DH_ + 4];
      float4 v2 = *(float4*)&vs[s*DH_ + 8];
      float pv = p[s];
      o[0] += pv*v0.x; o[1] += pv*v0.y; o[2]  += pv*v0.z; o[3]  += pv*v0.w;
      o[4] += pv*v1.x; o[5] += pv*v1.y; o[6]  += pv*v1.z; o[7]  += pv*v1.w;
      o[8] += pv*v2.x; o[9] += pv*v2.y; o[10] += pv*v2.z; o[11] += pv*v2.w;
    }
    float* orow = out + ((size_t)(b*S_ + i))*D_ + h*DH_;
    #pragma unroll
    for (int d = 0; d < DH_; d++) orow[d] = o[d]*inv;
  }
}

// ---------------- tiled GEMM: out[r][j] = act(A[r][:96] . W[j][:96] + bias[j]) ----------------
// 32 rows x 128 cols per block, 256 threads, 4x4 register tile, cols interleaved by 32.
template<int ACT>
__global__ __launch_bounds__(256) void k_gemm96(const float* __restrict__ A,
                                                const float* __restrict__ W,
                                                const float* __restrict__ bias,
                                                float* __restrict__ out,
                                                int nrows, int out_dim)
{
  __shared__ __align__(16) float a_s[32*100];
  __shared__ __align__(16) float w_s[128*100];
  __shared__ float b_s[128];
  int tid = threadIdx.x;
  int row0 = blockIdx.x*32, col0 = blockIdx.y*128;
  for (int idx = tid; idx < 32*24; idx += 256) {
    int r = idx/24, q = idx%24;
    *(float4*)&a_s[r*100 + q*4] = *(const float4*)&A[(size_t)(row0+r)*96 + q*4];
  }
  for (int idx = tid; idx < 128*24; idx += 256) {
    int j = idx/24, q = idx%24;
    int jj = col0 + j;
    float4 w;
    if (jj < out_dim) w = *(const float4*)&W[(size_t)jj*96 + q*4];
    else { w.x = w.y = w.z = w.w = 0.f; }
    *(float4*)&w_s[j*100 + q*4] = w;
  }
  if (tid < 128) b_s[tid] = (col0 + tid < out_dim) ? bias[col0 + tid] : 0.f;
  __syncthreads();
  int tc = tid % 32, tr = tid / 32;
  int r0 = tr*4;
  float acc[4][4];
  #pragma unroll
  for (int cc = 0; cc < 4; cc++) {
    float bv = b_s[tc + 32*cc];
    #pragma unroll
    for (int rr = 0; rr < 4; rr++) acc[rr][cc] = bv;
  }
  #pragma unroll
  for (int d = 0; d < 96; d += 4) {
    float4 a4[4], w4[4];
    #pragma unroll
    for (int rr = 0; rr < 4; rr++) a4[rr] = *(float4*)&a_s[(r0+rr)*100 + d];
    #pragma unroll
    for (int cc = 0; cc < 4; cc++) w4[cc] = *(float4*)&w_s[(tc + 32*cc)*100 + d];
    #pragma unroll
    for (int rr = 0; rr < 4; rr++)
      #pragma unroll
      for (int cc = 0; cc < 4; cc++)
        acc[rr][cc] += dot4f(a4[rr], w4[cc]);
  }
  #pragma unroll
  for (int rr = 0; rr < 4; rr++) {
    int row = row0 + r0 + rr;
    float* orow = out + (size_t)row*out_dim + col0;
    #pragma unroll
    for (int cc = 0; cc < 4; cc++) {
      int j = tc + 32*cc;
      if (col0 + j < out_dim) {
        float v = acc[rr][cc];
        if (ACT == 1) v = geluf(v);
        orow[j] = v;
      }
    }
  }
}

// ---------------- layernorm over 96, optional residual ----------------
__global__ __launch_bounds__(64) void k_ln(const float* __restrict__ in,
                                           const float* __restrict__ res,
                                           const float* __restrict__ g,
                                           const float* __restrict__ bb,
                                           float* __restrict__ out)
{
  int row = blockIdx.x; int t = threadIdx.x;
  size_t base = (size_t)row*96;
  float e0 = in[base + t] + (res ? res[base + t] : 0.f);
  float e1 = 0.f;
  if (t < 32) e1 = in[base + 64 + t] + (res ? res[base + 64 + t] : 0.f);
  float s = e0 + e1;
  for (int off = 32; off > 0; off >>= 1) s += __shfl_xor(s, off, 64);
  float mean = s * (1.f/96.f);
  float d0 = e0 - mean;
  float d1 = (t < 32) ? (e1 - mean) : 0.f;
  float v = d0*d0 + d1*d1;
  for (int off = 32; off > 0; off >>= 1) v += __shfl_xor(v, off, 64);
  float rstd = rsqrtf(v*(1.f/96.f) + 1e-5f);
  out[base + t] = d0*rstd*g[t] + bb[t];
  if (t < 32) out[base + 64 + t] = d1*rstd*g[64 + t] + bb[64 + t];
}

// ---------------- one full recurrent step, 16 batch rows per block ----------------
__global__ __launch_bounds__(256) void k_step(float* __restrict__ hidden,
    const float* __restrict__ kv_l,
    const float* __restrict__ ci_wi, const float* __restrict__ ci_bi,
    const float* __restrict__ ci_wo, const float* __restrict__ ci_bo,
    const float* __restrict__ ch_wi, const float* __restrict__ ch_bi,
    const float* __restrict__ ch_wo, const float* __restrict__ ch_bo,
    const float* __restrict__ gw, const float* __restrict__ gb,
    const float* __restrict__ w1, const float* __restrict__ b1,
    const float* __restrict__ w2, const float* __restrict__ b2,
    const float* __restrict__ n2g, const float* __restrict__ n2b,
    const float* __restrict__ n3g, const float* __restrict__ n3b)
{
  __shared__ __align__(16) float hs[16][100];
  __shared__ __align__(16) float bufA[16][100];
  __shared__ __align__(16) float bufB[16][100];
  __shared__ __align__(16) float bufC[16][100];
  __shared__ __align__(16) float f1b[16][200];
  int tid = threadIdx.x; int b0 = blockIdx.x*16;

  for (int idx = tid; idx < 16*24; idx += 256) {
    int r = idx/24, q = idx%24;
    *(float4*)&hs[r][q*4] = *(const float4*)&hidden[(size_t)(b0+r)*96 + q*4];
  }
  __syncthreads();

  // stage1: hq (j<96 from ci_wi rows 0..95) ; t2 = hidden@ch_wv (rows 192..287)
  for (int idx = tid; idx < 16*192; idx += 256) {
    int r = idx / 192, j = idx % 192;
    const float* wr = (j < 96) ? (ci_wi + (size_t)j*96) : (ch_wi + (size_t)(96 + j)*96);
    float acc = (j < 96) ? ci_bi[j] : ch_bi[96 + j];
    #pragma unroll
    for (int d = 0; d < 96; d += 4) {
      float4 a = *(float4*)&hs[r][d];
      float4 w = *(const float4*)&wr[d];
      acc += dot4f(a, w);
    }
    if (j < 96) bufA[r][j] = acc; else bufB[r][j-96] = acc;
  }
  __syncthreads();

  // stage2: cross-attention (query len 1, 50 keys) -> o1 in bufC
  if (tid < 128) {
    int r = tid >> 3, h = tid & 7;
    int b = b0 + r;
    float q[12];
    #pragma unroll
    for (int d = 0; d < 12; d++) q[d] = bufA[r][h*12 + d];
    float p[50]; float mx = -1e30f;
    #pragma unroll
    for (int s = 0; s < 50; s++) {
      const float* kr = kv_l + ((size_t)(b*50 + s))*192 + h*12;
      float4 k0 = *(const float4*)&kr[0];
      float4 k1 = *(const float4*)&kr[4];
      float4 k2 = *(const float4*)&kr[8];
      float acc = q[0]*k0.x + q[1]*k0.y + q[2]*k0.z + q[3]*k0.w
                + q[4]*k1.x + q[5]*k1.y + q[6]*k1.z + q[7]*k1.w
                + q[8]*k2.x + q[9]*k2.y + q[10]*k2.z + q[11]*k2.w;
      acc *= 0.28867513459481287f;
      p[s] = acc; mx = fmaxf(mx, acc);
    }
    float sum = 0.f;
    #pragma unroll
    for (int s = 0; s < 50; s++) { p[s] = expf(p[s] - mx); sum += p[s]; }
    float inv = 1.f / sum;
    float o[12];
    #pragma unroll
    for (int d = 0; d < 12; d++) o[d] = 0.f;
    #pragma unroll
    for (int s = 0; s < 50; s++) {
      const float* vr = kv_l + ((size_t)(b*50 + s))*192 + 96 + h*12;
      float4 v0 = *(const float4*)&vr[0];
      float4 v1 = *(const float4*)&vr[4];
      float4 v2 = *(const float4*)&vr[8];
      float pv = p[s];
      o[0] += pv*v0.x; o[1] += pv*v0.y; o[2]  += pv*v0.z; o[3]  += pv*v0.w;
      o[4] += pv*v1.x; o[5] += pv*v1.y; o[6]  += pv*v1.z; o[7]  += pv*v1.w;
      o[8] += pv*v2.x; o[9] += pv*v2.y; o[10] += pv*v2.z; o[11] += pv*v2.w;
    }
    #pragma unroll
    for (int d = 0; d < 12; d++) bufC[r][h*12 + d] = o[d]*inv;
  }
  __syncthreads();

  // stage3: c1 = o1@ci_wo^T + bo -> bufA ; c2 = t2@ch_wo^T + bo -> f1b
  for (int idx = tid; idx < 16*192; idx += 256) {
    int r = idx / 192, j = idx % 192;
    int jj = (j < 96) ? j : (j - 96);
    const float* ar = (j < 96) ? bufC[r] : bufB[r];
    const float* wr = ((j < 96) ? ci_wo : ch_wo) + (size_t)jj*96;
    float acc = (j < 96) ? ci_bo[jj] : ch_bo[jj];
    #pragma unroll
    for (int d = 0; d < 96; d += 4) {
      float4 a = *(float4*)&ar[d];
      float4 w = *(const float4*)&wr[d];
      acc += dot4f(a, w);
    }
    if (j < 96) bufA[r][j] = acc; else f1b[r][jj] = acc;
  }
  __syncthreads();

  // stage4: gate + combine + residual -> bufB, then LN(n2) in place
  for (int idx = tid; idx < 16*96; idx += 256) {
    int r = idx / 96, j = idx % 96;
    const float* gr = gw + (size_t)j*192;
    float acc = gb[j];
    #pragma unroll
    for (int d = 0; d < 96; d += 4) {
      float4 c1v = *(float4*)&bufA[r][d];
      float4 g1 = *(const float4*)&gr[d];
      float4 c2v = *(float4*)&f1b[r][d];
      float4 g2 = *(const float4*)&gr[96 + d];
      acc += dot4f(c1v, g1) + dot4f(c2v, g2);
    }
    float gv = 1.f/(1.f + expf(-acc));
    float pre = gv*bufA[r][j] + (1.f - gv)*f1b[r][j] + hs[r][j];
    bufB[r][j] = pre;
  }
  __syncthreads();
  {
    int r = tid / 16, l16 = tid % 16;
    float s1 = 0.f, s2 = 0.f;
    #pragma unroll
    for (int e = 0; e < 6; e++) { float v = bufB[r][l16*6 + e]; s1 += v; s2 += v*v; }
    for (int off = 8; off > 0; off >>= 1) { s1 += __shfl_xor(s1, off, 16); s2 += __shfl_xor(s2, off, 16); }
    float mean = s1*(1.f/96.f);
    float var = s2*(1.f/96.f) - mean*mean;
    float rstd = rsqrtf(var + 1e-5f);
    #pragma unroll
    for (int e = 0; e < 6; e++) {
      int j = l16*6 + e;
      bufB[r][j] = (bufB[r][j] - mean)*rstd*n2g[j] + n2b[j];
    }
  }
  __syncthreads();

  // stage5: f1 = gelu(gated@w1^T + b1) -> f1b (192 wide)
  for (int idx = tid; idx < 16*192; idx += 256) {
    int r = idx / 192, j = idx % 192;
    const float* wr = w1 + (size_t)j*96;
    float acc = b1[j];
    #pragma unroll
    for (int d = 0; d < 96; d += 4) {
      float4 a = *(float4*)&bufB[r][d];
      float4 w = *(const float4*)&wr[d];
      acc += dot4f(a, w);
    }
    f1b[r][j] = geluf(acc);
  }
  __syncthreads();

  // stage6: f = f1@w2^T + b2 + gated -> bufC, then LN(n3) -> hidden
  for (int idx = tid; idx < 16*96; idx += 256) {
    int r = idx / 96, j = idx % 96;
    const float* wr = w2 + (size_t)j*192;
    float acc = b2[j];
    #pragma unroll
    for (int d = 0; d < 192; d += 4) {
      float4 a = *(float4*)&f1b[r][d];
      float4 w = *(const float4*)&wr[d];
      acc += dot4f(a, w);
    }
    bufC[r][j] = acc + bufB[r][j];
  }
  __syncthreads();
  {
    int r = tid / 16, l16 = tid % 16;
    float s1 = 0.f, s2 = 0.f;
    #pragma unroll
    for (int e = 0; e < 6; e++) { float v = bufC[r][l16*6 + e]; s1 += v; s2 += v*v; }
    for (int off = 8; off > 0; off >>= 1) { s1 += __shfl_xor(s1, off, 16); s2 += __shfl_xor(s2, off, 16); }
    float mean = s1*(1.f/96.f);
    float var = s2*(1.f/96.f) - mean*mean;
    float rstd = rsqrtf(var + 1e-5f);
    #pragma unroll
    for (int e = 0; e < 6; e++) {
      int j = l16*6 + e;
      hidden[(size_t)(b0 + r)*96 + j] = (bufC[r][j] - mean)*rstd*n3g[j] + n3b[j];
    }
  }
}

extern "C" void kernel_launch(void* const* d_in, const int* in_sizes, int n_in,
                              void* d_out, int out_size, void* d_ws, size_t ws_size,
                              hipStream_t stream) {
  (void)in_sizes; (void)n_in; (void)out_size; (void)ws_size;
  const int* locations   = (const int*)d_in[0];
  const int* users       = (const int*)d_in[1];
  const int* start_mins  = (const int*)d_in[2];
  const int* weekdays    = (const int*)d_in[3];
  const float* loc_emb   = (const float*)d_in[4];
  const float* user_emb  = (const float*)d_in[5];
  const float* hour_emb  = (const float*)d_in[6];
  const float* wd_emb    = (const float*)d_in[7];
  const float* temp_w    = (const float*)d_in[8];
  const float* temp_b    = (const float*)d_in[9];
  const float* pos_embed = (const float*)d_in[10];
  const float* init_hidden = (const float*)d_in[11];
  const float* out_w1    = (const float*)d_in[12];
  const float* out_b1    = (const float*)d_in[13];
  const float* out_w2    = (const float*)d_in[14];
  const float* out_b2    = (const float*)d_in[15];
  const float* sa_wi = (const float*)d_in[16];
  const float* sa_bi = (const float*)d_in[17];
  const float* sa_wo = (const float*)d_in[18];
  const float* sa_bo = (const float*)d_in[19];
  const float* ci_wi = (const float*)d_in[20];
  const float* ci_bi = (const float*)d_in[21];
  const float* ci_wo = (const float*)d_in[22];
  const float* ci_bo = (const float*)d_in[23];
  const float* ch_wi = (const float*)d_in[24];
  const float* ch_bi = (const float*)d_in[25];
  const float* ch_wo = (const float*)d_in[26];
  const float* ch_bo = (const float*)d_in[27];
  const float* ffn_w1 = (const float*)d_in[28];
  const float* ffn_b1 = (const float*)d_in[29];
  const float* ffn_w2 = (const float*)d_in[30];
  const float* ffn_b2 = (const float*)d_in[31];
  const float* gate_w = (const float*)d_in[32];
  const float* gate_b = (const float*)d_in[33];
  const float* n1_g = (const float*)d_in[34];
  const float* n1_b = (const float*)d_in[35];
  const float* n2_g = (const float*)d_in[36];
  const float* n2_b = (const float*)d_in[37];
  const float* n3_g = (const float*)d_in[38];
  const float* n3_b = (const float*)d_in[39];

  float* ws = (float*)d_ws;
  float* x      = ws;                         // 1024*50*96 = 4915200
  float* attn_o = x + 4915200;                // 4915200 (also reused as a1)
  float* proj   = attn_o + 4915200;           // 4915200
  float* kv     = proj + 4915200;             // 3 * 51200*192 = 29491200
  float* hidden = kv + 29491200;              // 98304
  float* h1     = hidden + 98304;             // 98304

  k_embed<<<B_*S_, 96, 0, stream>>>(locations, users, start_mins, weekdays,
                                    loc_emb, user_emb, hour_emb, wd_emb,
                                    temp_w, temp_b, pos_embed, x);
  k_init<<<(B_*D_ + 255)/256, 256, 0, stream>>>(init_hidden, hidden);

  // Phase A: per-layer loop-invariant precompute
  for (int l = 0; l < L_; l++) {
    k_attn<<<B_*H_, 64, 0, stream>>>(x, sa_wi + (size_t)l*288*96, sa_bi + l*288, attn_o);
    k_gemm96<0><<<dim3(51200/32, 1), 256, 0, stream>>>(attn_o, sa_wo + (size_t)l*96*96,
                                                       sa_bo + l*96, proj, 51200, 96);
    k_ln<<<51200, 64, 0, stream>>>(proj, x, n1_g + l*96, n1_b + l*96, attn_o); // a1 := attn_o
    k_gemm96<0><<<dim3(51200/32, 2), 256, 0, stream>>>(attn_o, ci_wi + (size_t)l*288*96 + 96*96,
                                                       ci_bi + l*288 + 96,
                                                       kv + (size_t)l*9830400, 51200, 192);
  }

  // Phase B: 9 fused recurrent steps
  for (int c = 0; c < NC_; c++) {
    for (int l = 0; l < L_; l++) {
      k_step<<<B_/16, 256, 0, stream>>>(hidden, kv + (size_t)l*9830400,
          ci_wi + (size_t)l*288*96, ci_bi + l*288,
          ci_wo + (size_t)l*96*96,  ci_bo + l*96,
          ch_wi + (size_t)l*288*96, ch_bi + l*288,
          ch_wo + (size_t)l*96*96,  ch_bo + l*96,
          gate_w + (size_t)l*96*192, gate_b + l*96,
          ffn_w1 + (size_t)l*192*96, ffn_b1 + l*192,
          ffn_w2 + (size_t)l*96*192, ffn_b2 + l*96,
          n2_g + l*96, n2_b + l*96, n3_g + l*96, n3_b + l*96);
    }
  }

  // Head
  k_gemm96<1><<<dim3(1024/32, 1), 256, 0, stream>>>(hidden, out_w1, out_b1, h1, 1024, 96);
  k_gemm96<0><<<dim3(1024/32, (40000 + 127)/128), 256, 0, stream>>>(h1, out_w2, out_b2,
                                                                    (float*)d_out, 1024, 40000);
}

// Round 3
// 2259.614 us; speedup vs baseline: 4.4635x; 4.4635x over previous
//
#include <hip/hip_runtime.h>
#include <math.h>

#define B_ 1024
#define S_ 50
#define D_ 96
#define H_ 8
#define DH_ 12
#define DF_ 192
#define L_ 3
#define NC_ 3
#define V_ 40000

__device__ __forceinline__ float dot4f(float4 a, float4 b) {
  return a.x*b.x + a.y*b.y + a.z*b.z + a.w*b.w;
}
__device__ __forceinline__ float geluf(float v) {
  return 0.5f*v*(1.0f + erff(v*0.70710678118654752f));
}

// ---------------- embedding ----------------
__global__ void k_embed(const int* __restrict__ loc, const int* __restrict__ users,
                        const int* __restrict__ mins, const int* __restrict__ wd,
                        const float* __restrict__ loc_emb, const float* __restrict__ user_emb,
                        const float* __restrict__ hour_emb, const float* __restrict__ wd_emb,
                        const float* __restrict__ temp_w, const float* __restrict__ temp_b,
                        const float* __restrict__ pos, float* __restrict__ x)
{
  int bs = blockIdx.x; int b = bs / S_; int s = bs % S_;
  __shared__ float tmp[48];
  int t = threadIdx.x;
  if (t < 48) {
    int hr = (mins[bs] / 60) % 24;
    int w  = wd[bs];
    tmp[t] = (t < 24) ? hour_emb[hr*24 + t] : wd_emb[w*24 + (t-24)];
  }
  __syncthreads();
  int lc = loc[bs]; int u = users[b*S_];
  float acc = temp_b[t] + loc_emb[(size_t)lc*D_ + t] + user_emb[(size_t)u*D_ + t] + pos[s*D_ + t];
  const float* twr = temp_w + t*48;
  #pragma unroll
  for (int k = 0; k < 48; k++) acc += tmp[k] * twr[k];
  x[(size_t)bs*D_ + t] = acc;
}

// ---------------- init hidden ----------------
__global__ void k_init(const float* __restrict__ init_hidden, float* __restrict__ hidden) {
  int i = blockIdx.x*256 + threadIdx.x;
  if (i < B_*D_) hidden[i] = init_hidden[i % D_];
}

// ---------------- fused phase-A layer kernel: one block per batch ----------------
// QKV-proj -> 8-head attention -> Wo-proj + residual + LN(n1) -> KV-proj -> kv
// LDS map (floats): o_s [50][104] @0 ; xs [50][104] @5200 ; qkv_s [50][292] @10400
//                   kvout [50][196] @0 (aliases o_s+xs, both dead by then)
__global__ __launch_bounds__(512) void k_layerA(
    const float* __restrict__ x,
    const float* __restrict__ wi,  const float* __restrict__ bi,   // sa_wi [288][96], sa_bi
    const float* __restrict__ wo,  const float* __restrict__ bo,   // sa_wo [96][96]
    const float* __restrict__ n1g, const float* __restrict__ n1b,
    const float* __restrict__ kwi, const float* __restrict__ kbi,  // ci_wi rows 96..287, ci_bi+96
    float* __restrict__ kv)                                        // [51200][192] this layer
{
  __shared__ float lds[25000];
  float* o_s   = lds;          // [50][104]
  float* xs    = lds + 5200;   // [50][104]
  float* qkv_s = lds + 10400;  // [50][292]
  float* kvout = lds;          // [50][196]
  int tid = threadIdx.x;
  int b = blockIdx.x;
  const float* xb = x + (size_t)b*S_*D_;

  // 1. load x rows
  for (int idx = tid; idx < S_*24; idx += 512) {
    int r = idx/24, q = idx%24;
    *(float4*)&xs[r*104 + q*4] = *(const float4*)&xb[r*96 + q*4];
  }
  __syncthreads();

  // 2. QKV projection: tasks (g<72, s<50), 4 wi-rows per task; wi reads are wave-broadcast
  for (int idx = tid; idx < 72*50; idx += 512) {
    int g = idx/50, s = idx%50;
    const float* xr = &xs[s*104];
    const float* w0 = wi + (size_t)(g*4)*96;
    float acc0 = bi[4*g+0], acc1 = bi[4*g+1], acc2 = bi[4*g+2], acc3 = bi[4*g+3];
    #pragma unroll
    for (int d = 0; d < 96; d += 4) {
      float4 a = *(float4*)&xr[d];
      acc0 += dot4f(a, *(const float4*)&w0[0*96 + d]);
      acc1 += dot4f(a, *(const float4*)&w0[1*96 + d]);
      acc2 += dot4f(a, *(const float4*)&w0[2*96 + d]);
      acc3 += dot4f(a, *(const float4*)&w0[3*96 + d]);
    }
    float4 r4 = make_float4(acc0, acc1, acc2, acc3);
    *(float4*)&qkv_s[s*292 + 4*g] = r4;
  }
  __syncthreads();

  // 3. attention: 400 (h,i) tasks; LDS reads are (near-)broadcast within wave
  if (tid < 400) {
    int h = tid/50, i = tid%50;
    float q[DH_];
    #pragma unroll
    for (int d = 0; d < DH_; d++) q[d] = qkv_s[i*292 + h*12 + d];
    float p[S_]; float mx = -1e30f;
    #pragma unroll
    for (int s = 0; s < S_; s++) {
      const float* kr = &qkv_s[s*292 + 96 + h*12];
      float acc = 0.f;
      #pragma unroll
      for (int d = 0; d < DH_; d++) acc += q[d]*kr[d];
      acc *= 0.28867513459481287f;
      p[s] = acc; mx = fmaxf(mx, acc);
    }
    float sum = 0.f;
    #pragma unroll
    for (int s = 0; s < S_; s++) { p[s] = expf(p[s] - mx); sum += p[s]; }
    float inv = 1.f / sum;
    float o[DH_];
    #pragma unroll
    for (int d = 0; d < DH_; d++) o[d] = 0.f;
    #pragma unroll
    for (int s = 0; s < S_; s++) {
      const float* vr = &qkv_s[s*292 + 192 + h*12];
      float pv = p[s];
      #pragma unroll
      for (int d = 0; d < DH_; d++) o[d] += pv*vr[d];
    }
    #pragma unroll
    for (int d = 0; d < DH_; d++) o_s[i*104 + h*12 + d] = o[d]*inv;
  }
  __syncthreads();

  // 4. Wo-proj + residual -> pre-LN rows stored into qkv_s[s][0..95]
  for (int idx = tid; idx < 24*50; idx += 512) {
    int jg = idx/50, s = idx%50;
    const float* orow = &o_s[s*104];
    const float* w0 = wo + (size_t)(jg*4)*96;
    float acc0 = bo[4*jg+0], acc1 = bo[4*jg+1], acc2 = bo[4*jg+2], acc3 = bo[4*jg+3];
    #pragma unroll
    for (int d = 0; d < 96; d += 4) {
      float4 a = *(float4*)&orow[d];
      acc0 += dot4f(a, *(const float4*)&w0[0*96 + d]);
      acc1 += dot4f(a, *(const float4*)&w0[1*96 + d]);
      acc2 += dot4f(a, *(const float4*)&w0[2*96 + d]);
      acc3 += dot4f(a, *(const float4*)&w0[3*96 + d]);
    }
    int j = 4*jg;
    float4 r4 = make_float4(acc0 + xs[s*104 + j + 0],
                            acc1 + xs[s*104 + j + 1],
                            acc2 + xs[s*104 + j + 2],
                            acc3 + xs[s*104 + j + 3]);
    *(float4*)&qkv_s[s*292 + j] = r4;
  }
  __syncthreads();

  // 5. LN(n1) per row, in place
  if (tid < S_) {
    int i = tid;
    float s1 = 0.f, s2 = 0.f;
    #pragma unroll
    for (int j = 0; j < 96; j++) { float v = qkv_s[i*292 + j]; s1 += v; s2 += v*v; }
    float mean = s1*(1.f/96.f);
    float var = s2*(1.f/96.f) - mean*mean;
    float rstd = rsqrtf(var + 1e-5f);
    #pragma unroll
    for (int j = 0; j < 96; j++) {
      qkv_s[i*292 + j] = (qkv_s[i*292 + j] - mean)*rstd*n1g[j] + n1b[j];
    }
  }
  __syncthreads();

  // 6. KV projection from a1 (= qkv_s rows) -> kvout
  for (int idx = tid; idx < 48*50; idx += 512) {
    int jg = idx/50, s = idx%50;
    const float* ar = &qkv_s[s*292];
    const float* w0 = kwi + (size_t)(jg*4)*96;
    float acc0 = kbi[4*jg+0], acc1 = kbi[4*jg+1], acc2 = kbi[4*jg+2], acc3 = kbi[4*jg+3];
    #pragma unroll
    for (int d = 0; d < 96; d += 4) {
      float4 a = *(float4*)&ar[d];
      acc0 += dot4f(a, *(const float4*)&w0[0*96 + d]);
      acc1 += dot4f(a, *(const float4*)&w0[1*96 + d]);
      acc2 += dot4f(a, *(const float4*)&w0[2*96 + d]);
      acc3 += dot4f(a, *(const float4*)&w0[3*96 + d]);
    }
    float4 r4 = make_float4(acc0, acc1, acc2, acc3);
    *(float4*)&kvout[s*196 + 4*jg] = r4;
  }
  __syncthreads();

  // 7. coalesced write kv rows for this batch
  for (int idx = tid; idx < S_*48; idx += 512) {
    int r = idx/48, q = idx%48;
    *(float4*)&kv[(size_t)(b*S_ + r)*192 + q*4] = *(float4*)&kvout[r*196 + q*4];
  }
}

// ---------------- tiled GEMM (head1): 32 rows x 128 cols per block ----------------
template<int ACT>
__global__ __launch_bounds__(256) void k_gemm96(const float* __restrict__ A,
                                                const float* __restrict__ W,
                                                const float* __restrict__ bias,
                                                float* __restrict__ out,
                                                int nrows, int out_dim)
{
  __shared__ __align__(16) float a_s[32*100];
  __shared__ __align__(16) float w_s[128*100];
  __shared__ float b_s[128];
  int tid = threadIdx.x;
  int row0 = blockIdx.x*32, col0 = blockIdx.y*128;
  for (int idx = tid; idx < 32*24; idx += 256) {
    int r = idx/24, q = idx%24;
    *(float4*)&a_s[r*100 + q*4] = *(const float4*)&A[(size_t)(row0+r)*96 + q*4];
  }
  for (int idx = tid; idx < 128*24; idx += 256) {
    int j = idx/24, q = idx%24;
    int jj = col0 + j;
    float4 w;
    if (jj < out_dim) w = *(const float4*)&W[(size_t)jj*96 + q*4];
    else { w.x = w.y = w.z = w.w = 0.f; }
    *(float4*)&w_s[j*100 + q*4] = w;
  }
  if (tid < 128) b_s[tid] = (col0 + tid < out_dim) ? bias[col0 + tid] : 0.f;
  __syncthreads();
  int tc = tid % 32, tr = tid / 32;
  int r0 = tr*4;
  float acc[4][4];
  #pragma unroll
  for (int cc = 0; cc < 4; cc++) {
    float bv = b_s[tc + 32*cc];
    #pragma unroll
    for (int rr = 0; rr < 4; rr++) acc[rr][cc] = bv;
  }
  #pragma unroll
  for (int d = 0; d < 96; d += 4) {
    float4 a4[4], w4[4];
    #pragma unroll
    for (int rr = 0; rr < 4; rr++) a4[rr] = *(float4*)&a_s[(r0+rr)*100 + d];
    #pragma unroll
    for (int cc = 0; cc < 4; cc++) w4[cc] = *(float4*)&w_s[(tc + 32*cc)*100 + d];
    #pragma unroll
    for (int rr = 0; rr < 4; rr++)
      #pragma unroll
      for (int cc = 0; cc < 4; cc++)
        acc[rr][cc] += dot4f(a4[rr], w4[cc]);
  }
  #pragma unroll
  for (int rr = 0; rr < 4; rr++) {
    int row = row0 + r0 + rr;
    float* orow = out + (size_t)row*out_dim + col0;
    #pragma unroll
    for (int cc = 0; cc < 4; cc++) {
      int j = tc + 32*cc;
      if (col0 + j < out_dim) {
        float v = acc[rr][cc];
        if (ACT == 1) v = geluf(v);
        orow[j] = v;
      }
    }
  }
}

// ---------------- logits GEMM: column-stationary, W read exactly once ----------------
// grid 625 blocks (64 cols each), 256 threads; loops 8 chunks of 128 A-rows.
__global__ __launch_bounds__(256) void k_logits(const float* __restrict__ A,    // [1024][96]
                                                const float* __restrict__ W,    // [40000][96]
                                                const float* __restrict__ bias,
                                                float* __restrict__ out)        // [1024][40000]
{
  __shared__ __align__(16) float w_s[64*100];
  __shared__ __align__(16) float a_s[128*100];
  int tid = threadIdx.x;
  int col0 = blockIdx.x*64;
  for (int idx = tid; idx < 64*24; idx += 256) {
    int j = idx/24, q = idx%24;
    *(float4*)&w_s[j*100 + q*4] = *(const float4*)&W[(size_t)(col0+j)*96 + q*4];
  }
  int tc = tid % 16, tr = tid / 16;
  float bj[4];
  #pragma unroll
  for (int cc = 0; cc < 4; cc++) bj[cc] = bias[col0 + tc + 16*cc];

  for (int ch = 0; ch < 8; ch++) {
    __syncthreads();  // covers initial w_s load and protects a_s reuse
    for (int idx = tid; idx < 128*24; idx += 256) {
      int r = idx/24, q = idx%24;
      *(float4*)&a_s[r*100 + q*4] = *(const float4*)&A[(size_t)(ch*128 + r)*96 + q*4];
    }
    __syncthreads();
    float acc[8][4];
    #pragma unroll
    for (int rr = 0; rr < 8; rr++)
      #pragma unroll
      for (int cc = 0; cc < 4; cc++) acc[rr][cc] = bj[cc];
    #pragma unroll
    for (int d = 0; d < 96; d += 4) {
      float4 a4[8], w4[4];
      #pragma unroll
      for (int rr = 0; rr < 8; rr++) a4[rr] = *(float4*)&a_s[(tr*8+rr)*100 + d];
      #pragma unroll
      for (int cc = 0; cc < 4; cc++) w4[cc] = *(float4*)&w_s[(tc + 16*cc)*100 + d];
      #pragma unroll
      for (int rr = 0; rr < 8; rr++)
        #pragma unroll
        for (int cc = 0; cc < 4; cc++)
          acc[rr][cc] += dot4f(a4[rr], w4[cc]);
    }
    #pragma unroll
    for (int rr = 0; rr < 8; rr++) {
      int row = ch*128 + tr*8 + rr;
      float* orow = out + (size_t)row*V_ + col0;
      #pragma unroll
      for (int cc = 0; cc < 4; cc++) orow[tc + 16*cc] = acc[rr][cc];
    }
  }
}

// ---------------- one full recurrent step, 16 batch rows per block ----------------
__global__ __launch_bounds__(256) void k_step(float* __restrict__ hidden,
    const float* __restrict__ kv_l,
    const float* __restrict__ ci_wi, const float* __restrict__ ci_bi,
    const float* __restrict__ ci_wo, const float* __restrict__ ci_bo,
    const float* __restrict__ ch_wi, const float* __restrict__ ch_bi,
    const float* __restrict__ ch_wo, const float* __restrict__ ch_bo,
    const float* __restrict__ gw, const float* __restrict__ gb,
    const float* __restrict__ w1, const float* __restrict__ b1,
    const float* __restrict__ w2, const float* __restrict__ b2,
    const float* __restrict__ n2g, const float* __restrict__ n2b,
    const float* __restrict__ n3g, const float* __restrict__ n3b)
{
  __shared__ __align__(16) float hs[16][100];
  __shared__ __align__(16) float bufA[16][100];
  __shared__ __align__(16) float bufB[16][100];
  __shared__ __align__(16) float bufC[16][100];
  __shared__ __align__(16) float f1b[16][200];
  int tid = threadIdx.x; int b0 = blockIdx.x*16;

  for (int idx = tid; idx < 16*24; idx += 256) {
    int r = idx/24, q = idx%24;
    *(float4*)&hs[r][q*4] = *(const float4*)&hidden[(size_t)(b0+r)*96 + q*4];
  }
  __syncthreads();

  // stage1: hq (ci_wi rows 0..95) ; t2 = hidden@ch_wv (ch_wi rows 192..287)
  // mapping (r = idx%16, j = idx/16) -> weight reads are wave-broadcast
  for (int idx = tid; idx < 16*192; idx += 256) {
    int r = idx % 16, j = idx / 16;
    const float* wr = (j < 96) ? (ci_wi + (size_t)j*96) : (ch_wi + (size_t)(96 + j)*96);
    float acc = (j < 96) ? ci_bi[j] : ch_bi[96 + j];
    #pragma unroll
    for (int d = 0; d < 96; d += 4) {
      float4 a = *(float4*)&hs[r][d];
      float4 w = *(const float4*)&wr[d];
      acc += dot4f(a, w);
    }
    if (j < 96) bufA[r][j] = acc; else bufB[r][j-96] = acc;
  }
  __syncthreads();

  // stage2: cross-attention (query len 1, 50 keys) -> o1 in bufC
  if (tid < 128) {
    int r = tid >> 3, h = tid & 7;
    int b = b0 + r;
    float q[12];
    #pragma unroll
    for (int d = 0; d < 12; d++) q[d] = bufA[r][h*12 + d];
    float p[50]; float mx = -1e30f;
    #pragma unroll
    for (int s = 0; s < 50; s++) {
      const float* kr = kv_l + ((size_t)(b*50 + s))*192 + h*12;
      float4 k0 = *(const float4*)&kr[0];
      float4 k1 = *(const float4*)&kr[4];
      float4 k2 = *(const float4*)&kr[8];
      float acc = q[0]*k0.x + q[1]*k0.y + q[2]*k0.z + q[3]*k0.w
                + q[4]*k1.x + q[5]*k1.y + q[6]*k1.z + q[7]*k1.w
                + q[8]*k2.x + q[9]*k2.y + q[10]*k2.z + q[11]*k2.w;
      acc *= 0.28867513459481287f;
      p[s] = acc; mx = fmaxf(mx, acc);
    }
    float sum = 0.f;
    #pragma unroll
    for (int s = 0; s < 50; s++) { p[s] = expf(p[s] - mx); sum += p[s]; }
    float inv = 1.f / sum;
    float o[12];
    #pragma unroll
    for (int d = 0; d < 12; d++) o[d] = 0.f;
    #pragma unroll
    for (int s = 0; s < 50; s++) {
      const float* vr = kv_l + ((size_t)(b*50 + s))*192 + 96 + h*12;
      float4 v0 = *(const float4*)&vr[0];
      float4 v1 = *(const float4*)&vr[4];
      float4 v2 = *(const float4*)&vr[8];
      float pv = p[s];
      o[0] += pv*v0.x; o[1] += pv*v0.y; o[2]  += pv*v0.z; o[3]  += pv*v0.w;
      o[4] += pv*v1.x; o[5] += pv*v1.y; o[6]  += pv*v1.z; o[7]  += pv*v1.w;
      o[8] += pv*v2.x; o[9] += pv*v2.y; o[10] += pv*v2.z; o[11] += pv*v2.w;
    }
    #pragma unroll
    for (int d = 0; d < 12; d++) bufC[r][h*12 + d] = o[d]*inv;
  }
  __syncthreads();

  // stage3: c1 = o1@ci_wo^T + bo -> bufA ; c2 = t2@ch_wo^T + bo -> f1b
  for (int idx = tid; idx < 16*192; idx += 256) {
    int r = idx % 16, j = idx / 16;
    int jj = (j < 96) ? j : (j - 96);
    const float* ar = (j < 96) ? bufC[r] : bufB[r];
    const float* wr = ((j < 96) ? ci_wo : ch_wo) + (size_t)jj*96;
    float acc = (j < 96) ? ci_bo[jj] : ch_bo[jj];
    #pragma unroll
    for (int d = 0; d < 96; d += 4) {
      float4 a = *(float4*)&ar[d];
      float4 w = *(const float4*)&wr[d];
      acc += dot4f(a, w);
    }
    if (j < 96) bufA[r][j] = acc; else f1b[r][jj] = acc;
  }
  __syncthreads();

  // stage4: gate + combine + residual -> bufB, then LN(n2)
  for (int idx = tid; idx < 16*96; idx += 256) {
    int r = idx % 16, j = idx / 16;
    const float* gr = gw + (size_t)j*192;
    float acc = gb[j];
    #pragma unroll
    for (int d = 0; d < 96; d += 4) {
      float4 c1v = *(float4*)&bufA[r][d];
      float4 g1 = *(const float4*)&gr[d];
      float4 c2v = *(float4*)&f1b[r][d];
      float4 g2 = *(const float4*)&gr[96 + d];
      acc += dot4f(c1v, g1) + dot4f(c2v, g2);
    }
    float gv = 1.f/(1.f + expf(-acc));
    float pre = gv*bufA[r][j] + (1.f - gv)*f1b[r][j] + hs[r][j];
    bufB[r][j] = pre;
  }
  __syncthreads();
  {
    int r = tid / 16, l16 = tid % 16;
    float s1 = 0.f, s2 = 0.f;
    #pragma unroll
    for (int e = 0; e < 6; e++) { float v = bufB[r][l16*6 + e]; s1 += v; s2 += v*v; }
    for (int off = 8; off > 0; off >>= 1) { s1 += __shfl_xor(s1, off, 16); s2 += __shfl_xor(s2, off, 16); }
    float mean = s1*(1.f/96.f);
    float var = s2*(1.f/96.f) - mean*mean;
    float rstd = rsqrtf(var + 1e-5f);
    #pragma unroll
    for (int e = 0; e < 6; e++) {
      int j = l16*6 + e;
      bufB[r][j] = (bufB[r][j] - mean)*rstd*n2g[j] + n2b[j];
    }
  }
  __syncthreads();

  // stage5: f1 = gelu(gated@w1^T + b1) -> f1b (192 wide)
  for (int idx = tid; idx < 16*192; idx += 256) {
    int r = idx % 16, j = idx / 16;
    const float* wr = w1 + (size_t)j*96;
    float acc = b1[j];
    #pragma unroll
    for (int d = 0; d < 96; d += 4) {
      float4 a = *(float4*)&bufB[r][d];
      float4 w = *(const float4*)&wr[d];
      acc += dot4f(a, w);
    }
    f1b[r][j] = geluf(acc);
  }
  __syncthreads();

  // stage6: f = f1@w2^T + b2 + gated -> bufC, then LN(n3) -> hidden
  for (int idx = tid; idx < 16*96; idx += 256) {
    int r = idx % 16, j = idx / 16;
    const float* wr = w2 + (size_t)j*192;
    float acc = b2[j];
    #pragma unroll
    for (int d = 0; d < 192; d += 4) {
      float4 a = *(float4*)&f1b[r][d];
      float4 w = *(const float4*)&wr[d];
      acc += dot4f(a, w);
    }
    bufC[r][j] = acc + bufB[r][j];
  }
  __syncthreads();
  {
    int r = tid / 16, l16 = tid % 16;
    float s1 = 0.f, s2 = 0.f;
    #pragma unroll
    for (int e = 0; e < 6; e++) { float v = bufC[r][l16*6 + e]; s1 += v; s2 += v*v; }
    for (int off = 8; off > 0; off >>= 1) { s1 += __shfl_xor(s1, off, 16); s2 += __shfl_xor(s2, off, 16); }
    float mean = s1*(1.f/96.f);
    float var = s2*(1.f/96.f) - mean*mean;
    float rstd = rsqrtf(var + 1e-5f);
    #pragma unroll
    for (int e = 0; e < 6; e++) {
      int j = l16*6 + e;
      hidden[(size_t)(b0 + r)*96 + j] = (bufC[r][j] - mean)*rstd*n3g[j] + n3b[j];
    }
  }
}

extern "C" void kernel_launch(void* const* d_in, const int* in_sizes, int n_in,
                              void* d_out, int out_size, void* d_ws, size_t ws_size,
                              hipStream_t stream) {
  (void)in_sizes; (void)n_in; (void)out_size; (void)ws_size;
  const int* locations   = (const int*)d_in[0];
  const int* users       = (const int*)d_in[1];
  const int* start_mins  = (const int*)d_in[2];
  const int* weekdays    = (const int*)d_in[3];
  const float* loc_emb   = (const float*)d_in[4];
  const float* user_emb  = (const float*)d_in[5];
  const float* hour_emb  = (const float*)d_in[6];
  const float* wd_emb    = (const float*)d_in[7];
  const float* temp_w    = (const float*)d_in[8];
  const float* temp_b    = (const float*)d_in[9];
  const float* pos_embed = (const float*)d_in[10];
  const float* init_hidden = (const float*)d_in[11];
  const float* out_w1    = (const float*)d_in[12];
  const float* out_b1    = (const float*)d_in[13];
  const float* out_w2    = (const float*)d_in[14];
  const float* out_b2    = (const float*)d_in[15];
  const float* sa_wi = (const float*)d_in[16];
  const float* sa_bi = (const float*)d_in[17];
  const float* sa_wo = (const float*)d_in[18];
  const float* sa_bo = (const float*)d_in[19];
  const float* ci_wi = (const float*)d_in[20];
  const float* ci_bi = (const float*)d_in[21];
  const float* ci_wo = (const float*)d_in[22];
  const float* ci_bo = (const float*)d_in[23];
  const float* ch_wi = (const float*)d_in[24];
  const float* ch_bi = (const float*)d_in[25];
  const float* ch_wo = (const float*)d_in[26];
  const float* ch_bo = (const float*)d_in[27];
  const float* ffn_w1 = (const float*)d_in[28];
  const float* ffn_b1 = (const float*)d_in[29];
  const float* ffn_w2 = (const float*)d_in[30];
  const float* ffn_b2 = (const float*)d_in[31];
  const float* gate_w = (const float*)d_in[32];
  const float* gate_b = (const float*)d_in[33];
  const float* n1_g = (const float*)d_in[34];
  const float* n1_b = (const float*)d_in[35];
  const float* n2_g = (const float*)d_in[36];
  const float* n2_b = (const float*)d_in[37];
  const float* n3_g = (const float*)d_in[38];
  const float* n3_b = (const float*)d_in[39];

  float* ws = (float*)d_ws;
  float* x      = ws;                 // 1024*50*96 = 4,915,200
  float* kv     = x + 4915200;        // 3 * 51200*192 = 29,491,200
  float* hidden = kv + 29491200;      // 98,304
  float* h1     = hidden + 98304;     // 98,304   (total 34.6M floats = 138 MB)

  k_embed<<<B_*S_, 96, 0, stream>>>(locations, users, start_mins, weekdays,
                                    loc_emb, user_emb, hour_emb, wd_emb,
                                    temp_w, temp_b, pos_embed, x);
  k_init<<<(B_*D_ + 255)/256, 256, 0, stream>>>(init_hidden, hidden);

  // Phase A: one fused kernel per layer (x -> attn -> a1 -> kv), loop-invariant
  for (int l = 0; l < L_; l++) {
    k_layerA<<<B_, 512, 0, stream>>>(x,
        sa_wi + (size_t)l*288*96, sa_bi + l*288,
        sa_wo + (size_t)l*96*96,  sa_bo + l*96,
        n1_g + l*96, n1_b + l*96,
        ci_wi + (size_t)l*288*96 + 96*96, ci_bi + l*288 + 96,
        kv + (size_t)l*9830400);
  }

  // Phase B: 9 fused recurrent steps
  for (int c = 0; c < NC_; c++) {
    for (int l = 0; l < L_; l++) {
      k_step<<<B_/16, 256, 0, stream>>>(hidden, kv + (size_t)l*9830400,
          ci_wi + (size_t)l*288*96, ci_bi + l*288,
          ci_wo + (size_t)l*96*96,  ci_bo + l*96,
          ch_wi + (size_t)l*288*96, ch_bi + l*288,
          ch_wo + (size_t)l*96*96,  ch_bo + l*96,
          gate_w + (size_t)l*96*192, gate_b + l*96,
          ffn_w1 + (size_t)l*192*96, ffn_b1 + l*192,
          ffn_w2 + (size_t)l*96*192, ffn_b2 + l*96,
          n2_g + l*96, n2_b + l*96, n3_g + l*96, n3_b + l*96);
    }
  }

  // Head
  k_gemm96<1><<<dim3(B_/32, 1), 256, 0, stream>>>(hidden, out_w1, out_b1, h1, B_, 96);
  k_logits<<<V_/64, 256, 0, stream>>>(h1, out_w2, out_b2, (float*)d_out);
}